// Round 1
// baseline (1913.552 us; speedup 1.0000x reference)
//
#include <hip/hip_runtime.h>
#include <cstdint>
#include <cstddef>

#define B_ 256
#define T_ 250
#define D_ 700
#define H_ 1024
#define O_ 35

// ---------------------------------------------------------------------------
// Phase 1: d[m][n] = sum_k x_row(m)[k] * W[k][n] + bias[n]
// m = b*Tc + tt  ->  x row g = b*T + t0 + tt
// 128x128 tile, 256 threads, 8x8 micro (2x2 blocks of 4x4), BK=16, fp32.
// ---------------------------------------------------------------------------
__global__ __launch_bounds__(256, 2)
void d_gemm(const float* __restrict__ X, const float* __restrict__ W,
            const float* __restrict__ bias, float* __restrict__ C,
            int t0, int Tc)
{
    __shared__ float As[16][132];   // [k][m], +4 pad -> 2-way max on writes
    __shared__ float Bs[16][128];   // [k][n]
    const int tid = threadIdx.x;
    const int n0 = blockIdx.x * 128;
    const int m0 = blockIdx.y * 128;

    // A staging map: 2 float4 per thread (128 rows x 4 float4)
    const float* ap[2]; int ar[2], ak[2];
#pragma unroll
    for (int l = 0; l < 2; ++l) {
        int idx = tid + l * 256;
        int r = idx >> 2;          // 0..127
        int kq = idx & 3;          // float4 slot in k
        int m = m0 + r;
        int b = m / Tc, tt = m - b * Tc;
        ap[l] = X + (size_t)(b * T_ + t0 + tt) * D_;
        ar[l] = r; ak[l] = kq * 4;
    }
    // B staging map: 2 float4 per thread (16 rows x 32 float4)
    int bkr[2], bc[2];
#pragma unroll
    for (int l = 0; l < 2; ++l) {
        int idx = tid + l * 256;
        bkr[l] = idx >> 5;         // 0..15
        bc[l]  = (idx & 31) * 4;   // 0..124
    }
    const int r0 = (tid >> 4) * 4;
    const int c0 = (tid & 15) * 4;

    float acc[8][8];
#pragma unroll
    for (int i = 0; i < 8; ++i)
#pragma unroll
        for (int j = 0; j < 8; ++j) acc[i][j] = 0.f;

    for (int k0 = 0; k0 < D_; k0 += 16) {
#pragma unroll
        for (int l = 0; l < 2; ++l) {       // stage A (transposed)
            int k = k0 + ak[l];
            float4 v = make_float4(0.f, 0.f, 0.f, 0.f);
            if (k < D_) v = *reinterpret_cast<const float4*>(ap[l] + k);
            As[ak[l] + 0][ar[l]] = v.x;
            As[ak[l] + 1][ar[l]] = v.y;
            As[ak[l] + 2][ar[l]] = v.z;
            As[ak[l] + 3][ar[l]] = v.w;
        }
#pragma unroll
        for (int l = 0; l < 2; ++l) {       // stage B
            int k = k0 + bkr[l];
            float4 v = make_float4(0.f, 0.f, 0.f, 0.f);
            if (k < D_) v = *reinterpret_cast<const float4*>(W + (size_t)k * H_ + n0 + bc[l]);
            *reinterpret_cast<float4*>(&Bs[bkr[l]][bc[l]]) = v;
        }
        __syncthreads();
#pragma unroll
        for (int kk = 0; kk < 16; ++kk) {
            float a[8], bb[8];
            *(float4*)&a[0]  = *(const float4*)&As[kk][r0];
            *(float4*)&a[4]  = *(const float4*)&As[kk][r0 + 64];
            *(float4*)&bb[0] = *(const float4*)&Bs[kk][c0];
            *(float4*)&bb[4] = *(const float4*)&Bs[kk][c0 + 64];
#pragma unroll
            for (int i = 0; i < 8; ++i)
#pragma unroll
                for (int j = 0; j < 8; ++j)
                    acc[i][j] = fmaf(a[i], bb[j], acc[i][j]);
        }
        __syncthreads();
    }
    // epilogue: +bias, float4 stores
#pragma unroll
    for (int i = 0; i < 8; ++i) {
        int m = m0 + r0 + (i & 3) + (i >> 2) * 64;
#pragma unroll
        for (int cg = 0; cg < 2; ++cg) {
            int n = n0 + c0 + cg * 64;
            float4 v;
            v.x = acc[i][cg * 4 + 0] + bias[n + 0];
            v.y = acc[i][cg * 4 + 1] + bias[n + 1];
            v.z = acc[i][cg * 4 + 2] + bias[n + 2];
            v.w = acc[i][cg * 4 + 3] + bias[n + 3];
            *reinterpret_cast<float4*>(C + (size_t)m * H_ + n) = v;
        }
    }
}

// ---------------------------------------------------------------------------
// Phase 2: membrane scan over a T-chunk; one block per b, thread = h.
// Emits spikes as ballot bit-masks (16 u64 words per (b,t)).
// ---------------------------------------------------------------------------
__global__ __launch_bounds__(1024)
void scan_k(const float* __restrict__ dbuf, const float* __restrict__ tau,
            const float* __restrict__ memIn, const float* __restrict__ spkIn,
            float* __restrict__ memOut, float* __restrict__ spkOut,
            unsigned long long* __restrict__ bits, int t0, int Tc)
{
    const int b = blockIdx.x, h = threadIdx.x;
    const float al = 1.f / (1.f + expf(-tau[h]));
    const float om = 1.f - al;
    float mem = memIn[b * H_ + h];
    float spk = spkIn[b * H_ + h];   // spike0 is real-valued; used as-is first step
    const int lane = h & 63, w = h >> 6;
    for (int tt = 0; tt < Tc; ++tt) {
        float d = dbuf[(size_t)(b * Tc + tt) * H_ + h];
        mem = mem * al + om * d - spk;             // VTH = 1
        bool fire = (mem - 1.f) > 0.f;
        spk = fire ? 1.f : 0.f;
        unsigned long long msk = __ballot(fire);
        if (lane == 0) bits[((size_t)(b * T_ + t0 + tt) << 4) + w] = msk;
    }
    memOut[b * H_ + h] = mem;
    spkOut[b * H_ + h] = spk;
}

// ---------------------------------------------------------------------------
// Phase 3: per (b, t>10): logits = bit-masked sum of W_out rows + b_out,
// softmax in-registers, per-b reduction of probs into out[b][o].
// W_out addresses are wave-uniform -> scalar loads; FMA reads SGPR operand.
// ---------------------------------------------------------------------------
__global__ __launch_bounds__(256)
void out_k(const unsigned long long* __restrict__ bits,
           const float* __restrict__ Wo, const float* __restrict__ bo,
           float* __restrict__ out)
{
    __shared__ float sp[239][36];
    const int b = blockIdx.x, tid = threadIdx.x;
    const int t = tid + 11;
    if (t < T_) {
        float lg[35];
#pragma unroll
        for (int o = 0; o < 35; ++o) lg[o] = bo[o];
        const unsigned long long* bp = bits + ((size_t)(b * T_ + t) << 4);
#pragma unroll 1
        for (int w = 0; w < 16; ++w) {
            unsigned long long wb = bp[w];
            const float* wr = Wo + (size_t)(w * 64) * O_;
#pragma unroll 1
            for (int bit = 0; bit < 64; ++bit) {
                float s = (wb & 1ull) ? 1.f : 0.f;
                wb >>= 1;
                const float* wrr = wr + bit * O_;   // uniform across lanes
#pragma unroll
                for (int o = 0; o < 35; ++o) lg[o] = fmaf(s, wrr[o], lg[o]);
            }
        }
        float mx = lg[0];
#pragma unroll
        for (int o = 1; o < 35; ++o) mx = fmaxf(mx, lg[o]);
        float sum = 0.f;
#pragma unroll
        for (int o = 0; o < 35; ++o) { lg[o] = expf(lg[o] - mx); sum += lg[o]; }
        float inv = 1.f / sum;
#pragma unroll
        for (int o = 0; o < 35; ++o) sp[tid][o] = lg[o] * inv;
    }
    __syncthreads();
    if (tid < 35) {
        float a = 0.f;
        for (int r = 0; r < 239; ++r) a += sp[r][tid];   // t-order, matches ref
        out[b * O_ + tid] = a;
    }
}

// ---------------------------------------------------------------------------
extern "C" void kernel_launch(void* const* d_in, const int* in_sizes, int n_in,
                              void* d_out, int out_size, void* d_ws, size_t ws_size,
                              hipStream_t stream) {
    const float* x    = (const float*)d_in[0];
    const float* Wd   = (const float*)d_in[1];
    const float* bd   = (const float*)d_in[2];
    const float* Wo   = (const float*)d_in[3];
    const float* bo   = (const float*)d_in[4];
    const float* tau  = (const float*)d_in[5];
    const float* mem0 = (const float*)d_in[6];
    const float* spk0 = (const float*)d_in[7];
    float* out = (float*)d_out;

    char* ws = (char*)d_ws;
    const size_t bitsB = (size_t)B_ * T_ * 16 * sizeof(unsigned long long); // 8.192 MB
    unsigned long long* bits = (unsigned long long*)ws;
    float* memS = (float*)(ws + bitsB);
    float* spkS = memS + (size_t)B_ * H_;
    float* dbuf = spkS + (size_t)B_ * H_;
    const size_t fixed = bitsB + 2ull * B_ * H_ * sizeof(float);

    // pick largest chunk (divisor of 250) whose d-buffer fits the workspace;
    // prefer 50 so the chunk (52 MB) stays L3-resident between GEMM and scan.
    int Tc = 1;
    const int cands[6] = {50, 25, 10, 5, 2, 1};
    for (int ci = 0; ci < 6; ++ci) {
        if (fixed + (size_t)B_ * cands[ci] * H_ * sizeof(float) <= ws_size) { Tc = cands[ci]; break; }
    }
    const int nch = T_ / Tc;

    for (int c = 0; c < nch; ++c) {
        int t0 = c * Tc;
        dim3 grid(H_ / 128, (B_ * Tc) / 128);   // (8, 2*Tc)
        d_gemm<<<grid, 256, 0, stream>>>(x, Wd, bd, dbuf, t0, Tc);
        scan_k<<<B_, H_, 0, stream>>>(dbuf, tau,
                                      c == 0 ? mem0 : memS,
                                      c == 0 ? spk0 : spkS,
                                      memS, spkS, bits, t0, Tc);
    }
    out_k<<<B_, 256, 0, stream>>>(bits, Wo, bo, out);
}

// Round 2
// 515.087 us; speedup vs baseline: 3.7150x; 3.7150x over previous
//
#include <hip/hip_runtime.h>
#include <cstdint>
#include <cstddef>

#define B_ 256
#define T_ 250
#define D_ 700
#define KP 704
#define H_ 1024
#define O_ 35

typedef __attribute__((ext_vector_type(8))) short s16x8;
typedef __attribute__((ext_vector_type(4))) float fx4;

__device__ __forceinline__ unsigned short f2bf(float v) {
    union { float f; unsigned int u; } a; a.f = v;
    unsigned int r = a.u + 0x7FFFu + ((a.u >> 16) & 1u);
    return (unsigned short)(r >> 16);
}

__device__ __forceinline__ void glds16(const unsigned short* g, void* l) {
    __builtin_amdgcn_global_load_lds(
        (const __attribute__((address_space(1))) unsigned int*)(const void*)g,
        (__attribute__((address_space(3))) unsigned int*)l, 16, 0, 0);
}

// ---------------------------------------------------------------------------
// Split W_dense -> bf16 hi/lo, TRANSPOSED: WhT/WlT [1024][704], k>=700 zero.
// ---------------------------------------------------------------------------
__global__ __launch_bounds__(256)
void convW(const float* __restrict__ Wd, unsigned short* __restrict__ WhT,
           unsigned short* __restrict__ WlT)
{
    __shared__ float tile[32][33];
    const int tx = threadIdx.x, ty = threadIdx.y;
    const int bx = blockIdx.x, by = blockIdx.y;
#pragma unroll
    for (int i = 0; i < 4; ++i) {
        int k = by * 32 + ty + i * 8;
        int n = bx * 32 + tx;
        tile[ty + i * 8][tx] = (k < D_) ? Wd[(size_t)k * H_ + n] : 0.f;
    }
    __syncthreads();
#pragma unroll
    for (int i = 0; i < 4; ++i) {
        int n = bx * 32 + ty + i * 8;
        int k = by * 32 + tx;
        float v = tile[tx][ty + i * 8];
        unsigned short h = f2bf(v);
        union { unsigned int u; float f; } hf; hf.u = ((unsigned int)h) << 16;
        unsigned short lo = f2bf(v - hf.f);
        WhT[(size_t)n * KP + k] = h;
        WlT[(size_t)n * KP + k] = lo;
    }
}

// ---------------------------------------------------------------------------
// Split x chunk -> bf16 hi/lo packed rows [M][704]; row m -> x[b][t0+tt].
// ---------------------------------------------------------------------------
__global__ __launch_bounds__(256)
void convX(const float* __restrict__ X, unsigned short* __restrict__ xh,
           unsigned short* __restrict__ xl, int M, int Tc, int t0)
{
    int idx = blockIdx.x * 256 + threadIdx.x;
    if (idx >= M * 88) return;
    int m = idx / 88, s = idx - m * 88;
    int k = s * 8;
    int b = m / Tc, tt = m - b * Tc;
    const float* row = X + (size_t)(b * T_ + t0 + tt) * D_;
    float v[8];
#pragma unroll
    for (int j = 0; j < 4; ++j) v[j] = row[k + j];          // k+3 <= 699 always
    if (k + 4 < D_) {
#pragma unroll
        for (int j = 0; j < 4; ++j) v[4 + j] = row[k + 4 + j];
    } else {
#pragma unroll
        for (int j = 0; j < 4; ++j) v[4 + j] = 0.f;
    }
    unsigned int hw[4], lw[4];
#pragma unroll
    for (int j = 0; j < 4; ++j) {
        unsigned short h0 = f2bf(v[2 * j]), h1 = f2bf(v[2 * j + 1]);
        union { unsigned int u; float f; } a0, a1;
        a0.u = ((unsigned int)h0) << 16; a1.u = ((unsigned int)h1) << 16;
        unsigned short l0 = f2bf(v[2 * j] - a0.f), l1 = f2bf(v[2 * j + 1] - a1.f);
        hw[j] = (unsigned int)h0 | ((unsigned int)h1 << 16);
        lw[j] = (unsigned int)l0 | ((unsigned int)l1 << 16);
    }
    uint4 hv = make_uint4(hw[0], hw[1], hw[2], hw[3]);
    uint4 lv = make_uint4(lw[0], lw[1], lw[2], lw[3]);
    *reinterpret_cast<uint4*>(xh + (size_t)m * KP + k) = hv;
    *reinterpret_cast<uint4*>(xl + (size_t)m * KP + k) = lv;
}

// ---------------------------------------------------------------------------
// GEMM1: C[m][n] = sum_k (xh+xl)[m][k]*(Wh+Wl)[k][n] + bias[n]  (3 products)
// 128x128 tile, BK=64, 4 waves (2x2), 16x16x32 bf16 MFMA, global_load_lds
// staging with pre-swizzled source (slot ^= row&7) for conflict-free ds_read.
// ---------------------------------------------------------------------------
__global__ __launch_bounds__(256, 2)
void gemm1(const unsigned short* __restrict__ Ahp, const unsigned short* __restrict__ Alp,
           const unsigned short* __restrict__ Bhp, const unsigned short* __restrict__ Blp,
           const float* __restrict__ bias, float* __restrict__ C)
{
    __shared__ unsigned short lds[4 * 8192];  // Ah, Al, Bh, Bl: [128 rows][64 k]
    unsigned short* ldsAh = lds;
    unsigned short* ldsAl = lds + 8192;
    unsigned short* ldsBh = lds + 16384;
    unsigned short* ldsBl = lds + 24576;

    const int tid = threadIdx.x;
    const int l = tid & 63, w = tid >> 6;
    const int m0 = blockIdx.y * 128, n0 = blockIdx.x * 128;
    const int wm = w >> 1, wn = w & 1;

    // staging source offsets (ushort elements); swizzled slot within 128B row
    const int slot = (l & 7) ^ (l >> 3);
    int oA[4], oB[4];
#pragma unroll
    for (int j = 0; j < 4; ++j) {
        int r = j * 32 + w * 8 + (l >> 3);
        oA[j] = (m0 + r) * KP + slot * 8;
        oB[j] = (n0 + r) * KP + slot * 8;
    }
    const int ldsoff = w * 1024;  // bytes

    // fragment LDS byte offsets (swizzled read side)
    int aoff[2][4], boff[2][4];
#pragma unroll
    for (int kk = 0; kk < 2; ++kk)
#pragma unroll
        for (int f = 0; f < 4; ++f) {
            int rowA = wm * 64 + f * 16 + (l & 15);
            int rowB = wn * 64 + f * 16 + (l & 15);
            int c16 = kk * 4 + (l >> 4);
            aoff[kk][f] = rowA * 128 + ((c16 ^ (rowA & 7)) * 16);
            boff[kk][f] = rowB * 128 + ((c16 ^ (rowB & 7)) * 16);
        }

    fx4 acc[4][4];
#pragma unroll
    for (int i = 0; i < 4; ++i)
#pragma unroll
        for (int j = 0; j < 4; ++j) acc[i][j] = (fx4)0.f;

    for (int k0 = 0; k0 < KP; k0 += 64) {
#pragma unroll
        for (int j = 0; j < 4; ++j) {
            glds16(Ahp + oA[j] + k0, (char*)ldsAh + j * 4096 + ldsoff);
            glds16(Alp + oA[j] + k0, (char*)ldsAl + j * 4096 + ldsoff);
            glds16(Bhp + oB[j] + k0, (char*)ldsBh + j * 4096 + ldsoff);
            glds16(Blp + oB[j] + k0, (char*)ldsBl + j * 4096 + ldsoff);
        }
        __syncthreads();
#pragma unroll
        for (int kk = 0; kk < 2; ++kk) {
            s16x8 ah[4], al[4], bh[4], bl[4];
#pragma unroll
            for (int f = 0; f < 4; ++f) {
                ah[f] = *(const s16x8*)((const char*)ldsAh + aoff[kk][f]);
                al[f] = *(const s16x8*)((const char*)ldsAl + aoff[kk][f]);
                bh[f] = *(const s16x8*)((const char*)ldsBh + boff[kk][f]);
                bl[f] = *(const s16x8*)((const char*)ldsBl + boff[kk][f]);
            }
#pragma unroll
            for (int fm = 0; fm < 4; ++fm)
#pragma unroll
                for (int fn = 0; fn < 4; ++fn) {
                    acc[fm][fn] = __builtin_amdgcn_mfma_f32_16x16x32_bf16(ah[fm], bh[fn], acc[fm][fn], 0, 0, 0);
                    acc[fm][fn] = __builtin_amdgcn_mfma_f32_16x16x32_bf16(ah[fm], bl[fn], acc[fm][fn], 0, 0, 0);
                    acc[fm][fn] = __builtin_amdgcn_mfma_f32_16x16x32_bf16(al[fm], bh[fn], acc[fm][fn], 0, 0, 0);
                }
        }
        __syncthreads();
    }
    float bv[4];
#pragma unroll
    for (int fn = 0; fn < 4; ++fn) bv[fn] = bias[n0 + wn * 64 + fn * 16 + (l & 15)];
#pragma unroll
    for (int fm = 0; fm < 4; ++fm)
#pragma unroll
        for (int fn = 0; fn < 4; ++fn) {
            int col = n0 + wn * 64 + fn * 16 + (l & 15);
#pragma unroll
            for (int rg = 0; rg < 4; ++rg) {
                int row = m0 + wm * 64 + fm * 16 + (l >> 4) * 4 + rg;
                C[(size_t)row * H_ + col] = acc[fm][fn][rg] + bv[fn];
            }
        }
}

// ---------------------------------------------------------------------------
// Membrane scan over a T-chunk; emits ballot-bit spike masks.
// ---------------------------------------------------------------------------
__global__ __launch_bounds__(1024)
void scan_k(const float* __restrict__ dbuf, const float* __restrict__ tau,
            const float* __restrict__ memIn, const float* __restrict__ spkIn,
            float* __restrict__ memOut, float* __restrict__ spkOut,
            unsigned long long* __restrict__ bits, int t0, int Tc)
{
    const int b = blockIdx.x, h = threadIdx.x;
    const float al = 1.f / (1.f + expf(-tau[h]));
    const float om = 1.f - al;
    float mem = memIn[b * H_ + h];
    float spk = spkIn[b * H_ + h];
    const int lane = h & 63, w = h >> 6;
    for (int tt = 0; tt < Tc; ++tt) {
        float d = dbuf[(size_t)(b * Tc + tt) * H_ + h];
        mem = mem * al + om * d - spk;
        bool fire = (mem - 1.f) > 0.f;
        spk = fire ? 1.f : 0.f;
        unsigned long long msk = __ballot(fire);
        if (lane == 0) bits[((size_t)(b * T_ + t0 + tt) << 4) + w] = msk;
    }
    memOut[b * H_ + h] = mem;
    spkOut[b * H_ + h] = spk;
}

// ---------------------------------------------------------------------------
// Per (b,t>10) row: skip-zero bit walk, 4 lanes per row (4 words each),
// shuffle-combine, in-register softmax, write probs[r][35].
// ---------------------------------------------------------------------------
__global__ __launch_bounds__(256)
void out_probs(const unsigned long long* __restrict__ bits,
               const float* __restrict__ Wo, const float* __restrict__ bo,
               float* __restrict__ probs)
{
    const int tid = threadIdx.x;
    const int r = blockIdx.x * 64 + (tid >> 2);
    const int q = tid & 3;
    const int b = r / 239, tt = r - b * 239;
    const int t = tt + 11;
    float lg[35];
#pragma unroll
    for (int o = 0; o < 35; ++o) lg[o] = (q == 0) ? bo[o] : 0.f;
    const unsigned long long* bp = bits + ((size_t)(b * T_ + t) << 4) + q * 4;
#pragma unroll
    for (int w2 = 0; w2 < 4; ++w2) {
        unsigned long long wb = bp[w2];
        const float* wbase = Wo + (size_t)((q * 4 + w2) * 64) * O_;
        while (wb) {
            int i = __builtin_ctzll(wb);
            wb &= wb - 1;
            const float* wr = wbase + i * O_;
#pragma unroll
            for (int o = 0; o < 35; ++o) lg[o] += wr[o];
        }
    }
#pragma unroll
    for (int o = 0; o < 35; ++o) lg[o] += __shfl_xor(lg[o], 1);
#pragma unroll
    for (int o = 0; o < 35; ++o) lg[o] += __shfl_xor(lg[o], 2);
    float mx = lg[0];
#pragma unroll
    for (int o = 1; o < 35; ++o) mx = fmaxf(mx, lg[o]);
    float sum = 0.f;
#pragma unroll
    for (int o = 0; o < 35; ++o) { lg[o] = expf(lg[o] - mx); sum += lg[o]; }
    float inv = 1.f / sum;
    float* pr = probs + (size_t)r * O_;
#pragma unroll
    for (int o = 0; o < 35; ++o) if (o / 9 == q) pr[o] = lg[o] * inv;
}

// ---------------------------------------------------------------------------
// Reduce probs over t per b (deterministic, no atomics).
// ---------------------------------------------------------------------------
__global__ __launch_bounds__(256)
void acc_k(const float* __restrict__ probs, float* __restrict__ out)
{
    __shared__ float sp[64][36];
    const int b = blockIdx.x, tid = threadIdx.x;
    const int rl = tid >> 2, q = tid & 3;
    float a9[9];
#pragma unroll
    for (int j = 0; j < 9; ++j) a9[j] = 0.f;
    for (int c = 0; c < 239; c += 64) {
        int i = c + rl;
        if (i < 239) {
            const float* pr = probs + (size_t)(b * 239 + i) * O_ + q * 9;
#pragma unroll
            for (int j = 0; j < 9; ++j) if (j < 8 || q < 3) a9[j] += pr[j];
        }
    }
#pragma unroll
    for (int j = 0; j < 9; ++j) if (j < 8 || q < 3) sp[rl][q * 9 + j] = a9[j];
    __syncthreads();
    if (tid < 35) {
        float a = 0.f;
        for (int rr = 0; rr < 64; ++rr) a += sp[rr][tid];
        out[b * O_ + tid] = a;
    }
}

// ---------------------------------------------------------------------------
extern "C" void kernel_launch(void* const* d_in, const int* in_sizes, int n_in,
                              void* d_out, int out_size, void* d_ws, size_t ws_size,
                              hipStream_t stream) {
    const float* x    = (const float*)d_in[0];
    const float* Wd   = (const float*)d_in[1];
    const float* bd   = (const float*)d_in[2];
    const float* Wo   = (const float*)d_in[3];
    const float* bo   = (const float*)d_in[4];
    const float* tau  = (const float*)d_in[5];
    const float* mem0 = (const float*)d_in[6];
    const float* spk0 = (const float*)d_in[7];
    float* out = (float*)d_out;

    char* ws = (char*)d_ws;
    size_t off = 0;
    auto take = [&](size_t bytes) -> void* {
        void* p = ws + off;
        off = (off + bytes + 255) & ~(size_t)255;
        return p;
    };

    unsigned long long* bits = (unsigned long long*)take((size_t)B_ * T_ * 16 * 8);
    float* memS = (float*)take((size_t)B_ * H_ * 4);
    float* spkS = (float*)take((size_t)B_ * H_ * 4);
    unsigned short* WhT = (unsigned short*)take((size_t)H_ * KP * 2);
    unsigned short* WlT = (unsigned short*)take((size_t)H_ * KP * 2);
    float* probs = (float*)take((size_t)B_ * 239 * O_ * 4);
    const size_t fixed = off;

    int Tc = 1;
    const int cands[6] = {50, 25, 10, 5, 2, 1};
    for (int ci = 0; ci < 6; ++ci) {
        size_t per = ((size_t)B_ * cands[ci] * H_ * 4 + 256)
                   + 2 * ((size_t)B_ * cands[ci] * KP * 2 + 256);
        if (fixed + per <= ws_size) { Tc = cands[ci]; break; }
    }
    float* dbuf = (float*)take((size_t)B_ * Tc * H_ * 4);
    unsigned short* xh = (unsigned short*)take((size_t)B_ * Tc * KP * 2);
    unsigned short* xl = (unsigned short*)take((size_t)B_ * Tc * KP * 2);

    convW<<<dim3(32, 22), dim3(32, 8), 0, stream>>>(Wd, WhT, WlT);

    const int M = B_ * Tc;
    const int nch = T_ / Tc;
    for (int c = 0; c < nch; ++c) {
        int t0 = c * Tc;
        convX<<<(M * 88 + 255) / 256, 256, 0, stream>>>(x, xh, xl, M, Tc, t0);
        gemm1<<<dim3(8, M / 128), 256, 0, stream>>>(xh, xl, WhT, WlT, bd, dbuf);
        scan_k<<<B_, H_, 0, stream>>>(dbuf, tau,
                                      c == 0 ? mem0 : memS,
                                      c == 0 ? spk0 : spkS,
                                      memS, spkS, bits, t0, Tc);
    }
    out_probs<<<956, 256, 0, stream>>>(bits, Wo, bo, probs);
    acc_k<<<B_, 256, 0, stream>>>(probs, out);
}

// Round 3
// 476.886 us; speedup vs baseline: 4.0126x; 1.0801x over previous
//
#include <hip/hip_runtime.h>
#include <cstdint>
#include <cstddef>

#define B_ 256
#define T_ 250
#define D_ 700
#define KP 704
#define H_ 1024
#define O_ 35
#define NT 22   // 704/32 K-tiles

typedef __attribute__((ext_vector_type(8))) short s16x8;
typedef __attribute__((ext_vector_type(4))) float fx4;

__device__ __forceinline__ unsigned short f2bf(float v) {
    union { float f; unsigned int u; } a; a.f = v;
    unsigned int r = a.u + 0x7FFFu + ((a.u >> 16) & 1u);
    return (unsigned short)(r >> 16);
}

__device__ __forceinline__ void glds16(const unsigned short* g, void* l) {
    __builtin_amdgcn_global_load_lds(
        (const __attribute__((address_space(1))) unsigned int*)(const void*)g,
        (__attribute__((address_space(3))) unsigned int*)l, 16, 0, 0);
}

// ---------------------------------------------------------------------------
// Split W_dense -> bf16 hi/lo, TRANSPOSED: WhT/WlT [1024][704], k>=700 zero.
// ---------------------------------------------------------------------------
__global__ __launch_bounds__(256)
void convW(const float* __restrict__ Wd, unsigned short* __restrict__ WhT,
           unsigned short* __restrict__ WlT)
{
    __shared__ float tile[32][33];
    const int tx = threadIdx.x, ty = threadIdx.y;
    const int bx = blockIdx.x, by = blockIdx.y;
#pragma unroll
    for (int i = 0; i < 4; ++i) {
        int k = by * 32 + ty + i * 8;
        int n = bx * 32 + tx;
        tile[ty + i * 8][tx] = (k < D_) ? Wd[(size_t)k * H_ + n] : 0.f;
    }
    __syncthreads();
#pragma unroll
    for (int i = 0; i < 4; ++i) {
        int n = bx * 32 + ty + i * 8;
        int k = by * 32 + tx;
        float v = tile[tx][ty + i * 8];
        unsigned short h = f2bf(v);
        union { unsigned int u; float f; } hf; hf.u = ((unsigned int)h) << 16;
        unsigned short lo = f2bf(v - hf.f);
        WhT[(size_t)n * KP + k] = h;
        WlT[(size_t)n * KP + k] = lo;
    }
}

// ---------------------------------------------------------------------------
// Split x chunk -> bf16 hi/lo packed rows [M][704]; row m -> x[b][t0+tt].
// ---------------------------------------------------------------------------
__global__ __launch_bounds__(256)
void convX(const float* __restrict__ X, unsigned short* __restrict__ xh,
           unsigned short* __restrict__ xl, int M, int Tc, int t0)
{
    int idx = blockIdx.x * 256 + threadIdx.x;
    if (idx >= M * 88) return;
    int m = idx / 88, s = idx - m * 88;
    int k = s * 8;
    int b = m / Tc, tt = m - b * Tc;
    const float* row = X + (size_t)(b * T_ + t0 + tt) * D_;
    float v[8];
#pragma unroll
    for (int j = 0; j < 4; ++j) v[j] = row[k + j];
    if (k + 4 < D_) {
#pragma unroll
        for (int j = 0; j < 4; ++j) v[4 + j] = row[k + 4 + j];
    } else {
#pragma unroll
        for (int j = 0; j < 4; ++j) v[4 + j] = 0.f;
    }
    unsigned int hw[4], lw[4];
#pragma unroll
    for (int j = 0; j < 4; ++j) {
        unsigned short h0 = f2bf(v[2 * j]), h1 = f2bf(v[2 * j + 1]);
        union { unsigned int u; float f; } a0, a1;
        a0.u = ((unsigned int)h0) << 16; a1.u = ((unsigned int)h1) << 16;
        unsigned short l0 = f2bf(v[2 * j] - a0.f), l1 = f2bf(v[2 * j + 1] - a1.f);
        hw[j] = (unsigned int)h0 | ((unsigned int)h1 << 16);
        lw[j] = (unsigned int)l0 | ((unsigned int)l1 << 16);
    }
    *reinterpret_cast<uint4*>(xh + (size_t)m * KP + k) = make_uint4(hw[0], hw[1], hw[2], hw[3]);
    *reinterpret_cast<uint4*>(xl + (size_t)m * KP + k) = make_uint4(lw[0], lw[1], lw[2], lw[3]);
}

// ---------------------------------------------------------------------------
// GEMM1: 256x256 tile, BK=32, 8 waves (2Mx4N), 3-product bf16 split MFMA.
// Double-buffered LDS (128 KB), stage-early + single barrier per K-tile,
// XOR swizzle (slot ^ (row>>1)&3) on both stage-source and ds_read side.
// ---------------------------------------------------------------------------
__global__ __launch_bounds__(512, 2)
void gemm1(const unsigned short* __restrict__ Ahp, const unsigned short* __restrict__ Alp,
           const unsigned short* __restrict__ Bhp, const unsigned short* __restrict__ Blp,
           const float* __restrict__ bias, float* __restrict__ C)
{
    extern __shared__ char smem[];   // 2 bufs x 4 mats x 16 KB = 128 KB
    const int tid = threadIdx.x;
    const int l = tid & 63, w = tid >> 6;
    const int wm = w >> 2, wn = w & 3;          // 2 x 4 wave grid

    // bijective XCD swizzle
    const int nwg = gridDim.x, orig = blockIdx.x;
    const int xcd = orig & 7, idx = orig >> 3;
    const int q = nwg >> 3, r = nwg & 7;
    const int swz = (xcd < r ? xcd * (q + 1) : r * (q + 1) + (xcd - r) * q) + idx;
    const int by = swz >> 2, bx = swz & 3;
    const int m0 = by * 256, n0 = bx * 256;

    // stage maps: 4 matrices x 2 loads; 1024 slots of 16B per 16KB matrix
    const unsigned short* gptr[4] = {Ahp, Alp, Bhp, Blp};
    int goff[4][2];
#pragma unroll
    for (int mt = 0; mt < 4; ++mt) {
        int R0 = (mt < 2) ? m0 : n0;
#pragma unroll
        for (int j = 0; j < 2; ++j) {
            int slotlin = j * 512 + tid;
            int rr = slotlin >> 2, ss = slotlin & 3;
            goff[mt][j] = (R0 + rr) * KP + ((ss ^ ((rr >> 1) & 3)) << 3);
        }
    }
    const int wbase = w * 1024;   // bytes, wave-uniform LDS stage base

    // fragment read offsets (bytes within one 128KB-half buffer)
    int aH[8], aL[8], bH[4], bL[4];
#pragma unroll
    for (int fm = 0; fm < 8; ++fm) {
        int ra = wm * 128 + fm * 16 + (l & 15);
        int sw = (((l >> 4) ^ ((ra >> 1) & 3)) << 4);
        aH[fm] = ra * 64 + sw;
        aL[fm] = 16384 + ra * 64 + sw;
    }
#pragma unroll
    for (int fn = 0; fn < 4; ++fn) {
        int rb = wn * 64 + fn * 16 + (l & 15);
        int sw = (((l >> 4) ^ ((rb >> 1) & 3)) << 4);
        bH[fn] = 32768 + rb * 64 + sw;
        bL[fn] = 49152 + rb * 64 + sw;
    }

    fx4 acc[8][4];
#pragma unroll
    for (int i = 0; i < 8; ++i)
#pragma unroll
        for (int j = 0; j < 4; ++j) acc[i][j] = (fx4)0.f;

    auto stage = [&](int buf, int t) {
        const int kadd = t * 32;
        char* base = smem + buf * 65536;
#pragma unroll
        for (int mt = 0; mt < 4; ++mt)
#pragma unroll
            for (int j = 0; j < 2; ++j)
                glds16(gptr[mt] + goff[mt][j] + kadd,
                       base + mt * 16384 + j * 8192 + wbase);
    };

    stage(0, 0);
    __syncthreads();

    for (int t = 0; t < NT; ++t) {
        if (t + 1 < NT) stage((t + 1) & 1, t + 1);
        const char* cb = smem + (t & 1) * 65536;

        s16x8 bhf[4], blf[4], ahf[4], alf[4];
#pragma unroll
        for (int fn = 0; fn < 4; ++fn) {
            bhf[fn] = *(const s16x8*)(cb + bH[fn]);
            blf[fn] = *(const s16x8*)(cb + bL[fn]);
        }
#pragma unroll
        for (int fm = 0; fm < 4; ++fm) {
            ahf[fm] = *(const s16x8*)(cb + aH[fm]);
            alf[fm] = *(const s16x8*)(cb + aL[fm]);
        }
        __builtin_amdgcn_s_setprio(1);
#pragma unroll
        for (int fm = 0; fm < 4; ++fm)
#pragma unroll
            for (int fn = 0; fn < 4; ++fn) {
                acc[fm][fn] = __builtin_amdgcn_mfma_f32_16x16x32_bf16(ahf[fm], bhf[fn], acc[fm][fn], 0, 0, 0);
                acc[fm][fn] = __builtin_amdgcn_mfma_f32_16x16x32_bf16(ahf[fm], blf[fn], acc[fm][fn], 0, 0, 0);
                acc[fm][fn] = __builtin_amdgcn_mfma_f32_16x16x32_bf16(alf[fm], bhf[fn], acc[fm][fn], 0, 0, 0);
            }
        __builtin_amdgcn_s_setprio(0);
#pragma unroll
        for (int fm = 0; fm < 4; ++fm) {
            ahf[fm] = *(const s16x8*)(cb + aH[fm + 4]);
            alf[fm] = *(const s16x8*)(cb + aL[fm + 4]);
        }
        __builtin_amdgcn_s_setprio(1);
#pragma unroll
        for (int fm = 0; fm < 4; ++fm)
#pragma unroll
            for (int fn = 0; fn < 4; ++fn) {
                acc[fm + 4][fn] = __builtin_amdgcn_mfma_f32_16x16x32_bf16(ahf[fm], bhf[fn], acc[fm + 4][fn], 0, 0, 0);
                acc[fm + 4][fn] = __builtin_amdgcn_mfma_f32_16x16x32_bf16(ahf[fm], blf[fn], acc[fm + 4][fn], 0, 0, 0);
                acc[fm + 4][fn] = __builtin_amdgcn_mfma_f32_16x16x32_bf16(alf[fm], bhf[fn], acc[fm + 4][fn], 0, 0, 0);
            }
        __builtin_amdgcn_s_setprio(0);
        __syncthreads();   // drains vmcnt (stage t+1) + lgkm; buffers swap safely
    }

    float bv[4];
#pragma unroll
    for (int fn = 0; fn < 4; ++fn) bv[fn] = bias[n0 + wn * 64 + fn * 16 + (l & 15)];
#pragma unroll
    for (int fm = 0; fm < 8; ++fm) {
        int rowb = m0 + wm * 128 + fm * 16 + (l >> 4) * 4;
#pragma unroll
        for (int fn = 0; fn < 4; ++fn) {
            int col = n0 + wn * 64 + fn * 16 + (l & 15);
#pragma unroll
            for (int rg = 0; rg < 4; ++rg)
                C[(size_t)(rowb + rg) * H_ + col] = acc[fm][fn][rg] + bv[fn];
        }
    }
}

// ---------------------------------------------------------------------------
// Membrane scan: grid (B, 16), 64 threads; each wave owns 64 h-channels.
// ---------------------------------------------------------------------------
__global__ __launch_bounds__(64)
void scan2(const float* __restrict__ dbuf, const float* __restrict__ tau,
           const float* __restrict__ memIn, const float* __restrict__ spkIn,
           float* __restrict__ memOut, float* __restrict__ spkOut,
           unsigned long long* __restrict__ bits, int t0, int Tc)
{
    const int b = blockIdx.x, w = blockIdx.y;
    const int lane = threadIdx.x;
    const int h = w * 64 + lane;
    const float al = 1.f / (1.f + expf(-tau[h]));
    const float om = 1.f - al;
    float mem = memIn[b * H_ + h];
    float spk = spkIn[b * H_ + h];
    const float* dp = dbuf + (size_t)b * Tc * H_ + h;
    unsigned long long* bp = bits + (((size_t)(b * T_ + t0)) << 4) + w;
    for (int tt = 0; tt < Tc; ++tt) {
        float d = dp[(size_t)tt * H_];
        mem = mem * al + om * d - spk;
        bool fire = (mem - 1.f) > 0.f;
        spk = fire ? 1.f : 0.f;
        unsigned long long msk = __ballot(fire);
        if (lane == 0) bp[(size_t)tt << 4] = msk;
    }
    memOut[b * H_ + h] = mem;
    spkOut[b * H_ + h] = spk;
}

// ---------------------------------------------------------------------------
// Per (b,t>10) row: skip-zero bit walk, 4 lanes per row, shuffle-combine,
// in-register softmax, write probs[r][35].
// ---------------------------------------------------------------------------
__global__ __launch_bounds__(256)
void out_probs(const unsigned long long* __restrict__ bits,
               const float* __restrict__ Wo, const float* __restrict__ bo,
               float* __restrict__ probs)
{
    const int tid = threadIdx.x;
    const int r = blockIdx.x * 64 + (tid >> 2);
    const int q = tid & 3;
    const int b = r / 239, tt = r - b * 239;
    const int t = tt + 11;
    float lg[35];
#pragma unroll
    for (int o = 0; o < 35; ++o) lg[o] = (q == 0) ? bo[o] : 0.f;
    const unsigned long long* bp = bits + ((size_t)(b * T_ + t) << 4) + q * 4;
#pragma unroll
    for (int w2 = 0; w2 < 4; ++w2) {
        unsigned long long wb = bp[w2];
        const float* wbase = Wo + (size_t)((q * 4 + w2) * 64) * O_;
        while (wb) {
            int i = __builtin_ctzll(wb);
            wb &= wb - 1;
            const float* wr = wbase + i * O_;
#pragma unroll
            for (int o = 0; o < 35; ++o) lg[o] += wr[o];
        }
    }
#pragma unroll
    for (int o = 0; o < 35; ++o) lg[o] += __shfl_xor(lg[o], 1);
#pragma unroll
    for (int o = 0; o < 35; ++o) lg[o] += __shfl_xor(lg[o], 2);
    float mx = lg[0];
#pragma unroll
    for (int o = 1; o < 35; ++o) mx = fmaxf(mx, lg[o]);
    float sum = 0.f;
#pragma unroll
    for (int o = 0; o < 35; ++o) { lg[o] = expf(lg[o] - mx); sum += lg[o]; }
    float inv = 1.f / sum;
    float* pr = probs + (size_t)r * O_;
#pragma unroll
    for (int o = 0; o < 35; ++o) if (o / 9 == q) pr[o] = lg[o] * inv;
}

// ---------------------------------------------------------------------------
// Reduce probs over t per b (deterministic, no atomics).
// ---------------------------------------------------------------------------
__global__ __launch_bounds__(256)
void acc_k(const float* __restrict__ probs, float* __restrict__ out)
{
    __shared__ float sp[64][36];
    const int b = blockIdx.x, tid = threadIdx.x;
    const int rl = tid >> 2, q = tid & 3;
    float a9[9];
#pragma unroll
    for (int j = 0; j < 9; ++j) a9[j] = 0.f;
    for (int c = 0; c < 239; c += 64) {
        int i = c + rl;
        if (i < 239) {
            const float* pr = probs + (size_t)(b * 239 + i) * O_ + q * 9;
#pragma unroll
            for (int j = 0; j < 9; ++j) if (j < 8 || q < 3) a9[j] += pr[j];
        }
    }
#pragma unroll
    for (int j = 0; j < 9; ++j) if (j < 8 || q < 3) sp[rl][q * 9 + j] = a9[j];
    __syncthreads();
    if (tid < 35) {
        float a = 0.f;
        for (int rr = 0; rr < 64; ++rr) a += sp[rr][tid];
        out[b * O_ + tid] = a;
    }
}

// ---------------------------------------------------------------------------
extern "C" void kernel_launch(void* const* d_in, const int* in_sizes, int n_in,
                              void* d_out, int out_size, void* d_ws, size_t ws_size,
                              hipStream_t stream) {
    const float* x    = (const float*)d_in[0];
    const float* Wd   = (const float*)d_in[1];
    const float* bd   = (const float*)d_in[2];
    const float* Wo   = (const float*)d_in[3];
    const float* bo   = (const float*)d_in[4];
    const float* tau  = (const float*)d_in[5];
    const float* mem0 = (const float*)d_in[6];
    const float* spk0 = (const float*)d_in[7];
    float* out = (float*)d_out;

    char* ws = (char*)d_ws;
    size_t off = 0;
    auto take = [&](size_t bytes) -> void* {
        void* p = ws + off;
        off = (off + bytes + 255) & ~(size_t)255;
        return p;
    };

    unsigned long long* bits = (unsigned long long*)take((size_t)B_ * T_ * 16 * 8);
    float* memS = (float*)take((size_t)B_ * H_ * 4);
    float* spkS = (float*)take((size_t)B_ * H_ * 4);
    unsigned short* WhT = (unsigned short*)take((size_t)H_ * KP * 2);
    unsigned short* WlT = (unsigned short*)take((size_t)H_ * KP * 2);
    float* probs = (float*)take((size_t)B_ * 239 * O_ * 4);
    const size_t fixed = off;

    int Tc = 1;
    const int cands[6] = {50, 25, 10, 5, 2, 1};
    for (int ci = 0; ci < 6; ++ci) {
        size_t per = ((size_t)B_ * cands[ci] * H_ * 4 + 256)
                   + 2 * ((size_t)B_ * cands[ci] * KP * 2 + 256);
        if (fixed + per <= ws_size) { Tc = cands[ci]; break; }
    }
    float* dbuf = (float*)take((size_t)B_ * Tc * H_ * 4);
    unsigned short* xh = (unsigned short*)take((size_t)B_ * Tc * KP * 2);
    unsigned short* xl = (unsigned short*)take((size_t)B_ * Tc * KP * 2);

    convW<<<dim3(32, 22), dim3(32, 8), 0, stream>>>(Wd, WhT, WlT);

    const int M = B_ * Tc;
    const int nch = T_ / Tc;
    for (int c = 0; c < nch; ++c) {
        int t0 = c * Tc;
        convX<<<(M * 88 + 255) / 256, 256, 0, stream>>>(x, xh, xl, M, Tc, t0);
        gemm1<<<(M / 256) * 4, 512, 131072, stream>>>(xh, xl, WhT, WlT, bd, dbuf);
        scan2<<<dim3(B_, 16), 64, 0, stream>>>(dbuf, tau,
                                               c == 0 ? mem0 : memS,
                                               c == 0 ? spk0 : spkS,
                                               memS, spkS, bits, t0, Tc);
    }
    out_probs<<<956, 256, 0, stream>>>(bits, Wo, bo, probs);
    acc_k<<<B_, 256, 0, stream>>>(probs, out);
}